// Round 1
// 1086.459 us; speedup vs baseline: 1.0920x; 1.0920x over previous
//
#include <hip/hip_runtime.h>

// lqformerattention on MI355X (gfx950).
// Pipeline: proj_qk     (fused, grid.z selects q|k)  -> qhat(,pre-scaled by 1/sqrt32)/khat [8192][512] f16
//           proj_gemm<1>(value) -> vhatT[b][2048 feat][1024 kpos] f16 (transposed)
//           attn_fused: per (b,h,16 q-rows): QK^T mfma -> exp -> P (LDS, swizzled, UNNORMALIZED)
//                       -> rowsum -> PV mfma (scale by 1/l in epilogue) -> O, then stream weights.
// All matmul math in fp16 MFMA (16x16x32) with fp32 accumulation; softmax in fp32.
// Workspace usage: 48 MiB (qhat 8 + khat 8 + vhatT 32).

typedef _Float16 f16;
typedef _Float16 f16x8 __attribute__((ext_vector_type(8)));
typedef _Float16 f16x4 __attribute__((ext_vector_type(4)));
typedef float f32x4 __attribute__((ext_vector_type(4)));
typedef float f32x8 __attribute__((ext_vector_type(8)));

// ---------------------------------------------------------------------------
// proj_body: Y = (X(MxK) @ W(NxK)^T + bias) * oscale, fp32 in, f16 out.
// 128x128 block tile, BK=32, 256 threads = 4 waves in 2x2, mfma_f32_16x16x32_f16.
// LDS holds A/B tiles in *fragment order* (slot (mtile,lane) == the half8 lane
// needs) -> staging writes and frag reads are lane-linear b128, conflict-free.
// Software pipeline: global loads for k-step t+1 issue between the two barriers
// of step t, overlapping HBM latency with the 16 MFMAs (latency was exposed
// before: load -> cvt -> LDS write all serial at iteration top).
// MODE 0: natural Y[M][N].  MODE 1: v-proj transposed Y[(b*2048+n)*1024 + kpos].
// ---------------------------------------------------------------------------
template <int MODE>
__device__ __forceinline__ void proj_body(
    const float* __restrict__ X, const float* __restrict__ W,
    const float* __restrict__ bias, f16* __restrict__ Y, int K, int N,
    float oscale, f16* Asf, f16* Bsf) {
  const int t = threadIdx.x;
  const int lane = t & 63;
  const int w = t >> 6;
  const int wm = w >> 1, wn = w & 1;
  const int quad = lane >> 4, col = lane & 15;
  const long m0 = (long)blockIdx.x * 128;
  const int n0 = blockIdx.y * 128;

  f32x4 acc[4][4];
#pragma unroll
  for (int i = 0; i < 4; ++i)
#pragma unroll
    for (int j = 0; j < 4; ++j) acc[i][j] = (f32x4){0.f, 0.f, 0.f, 0.f};

  // staging geometry (invariant across k-steps)
  const int kq = t & 3;          // which 8-wide k chunk
  const int row0 = t >> 2;       // tile-local rows row0 and row0+64
  const int row1 = row0 + 64;
  const float* xp0 = X + (m0 + row0) * (long)K + kq * 8;
  const float* xp1 = X + (m0 + row1) * (long)K + kq * 8;
  const float* wp0 = W + ((long)n0 + row0) * (long)K + kq * 8;
  const float* wp1 = W + ((long)n0 + row1) * (long)K + kq * 8;
  const int l0 = (((row0 >> 4) * 64) + (row0 & 15) + (kq << 4)) * 8;
  const int l1 = (((row1 >> 4) * 64) + (row1 & 15) + (kq << 4)) * 8;

  // prologue: first tile into registers
  f32x8 xa0 = *(const f32x8*)xp0;
  f32x8 xa1 = *(const f32x8*)xp1;
  f32x8 wa0 = *(const f32x8*)wp0;
  f32x8 wa1 = *(const f32x8*)wp1;

  for (int k0 = 0; k0 < K; k0 += 32) {
    // commit staged registers (k-step k0) to LDS as f16 fragments
    *(f16x8*)&Asf[l0] = __builtin_convertvector(xa0, f16x8);
    *(f16x8*)&Asf[l1] = __builtin_convertvector(xa1, f16x8);
    *(f16x8*)&Bsf[l0] = __builtin_convertvector(wa0, f16x8);
    *(f16x8*)&Bsf[l1] = __builtin_convertvector(wa1, f16x8);
    __syncthreads();
    // prefetch k-step k0+32 (in flight across the MFMA block below)
    if (k0 + 32 < K) {
      xa0 = *(const f32x8*)(xp0 + k0 + 32);
      xa1 = *(const f32x8*)(xp1 + k0 + 32);
      wa0 = *(const f32x8*)(wp0 + k0 + 32);
      wa1 = *(const f32x8*)(wp1 + k0 + 32);
    }
    f16x8 a[4], b[4];
#pragma unroll
    for (int i = 0; i < 4; ++i)
      a[i] = *(const f16x8*)&Asf[((wm * 4 + i) * 64 + lane) * 8];
#pragma unroll
    for (int j = 0; j < 4; ++j)
      b[j] = *(const f16x8*)&Bsf[((wn * 4 + j) * 64 + lane) * 8];
#pragma unroll
    for (int i = 0; i < 4; ++i)
#pragma unroll
      for (int j = 0; j < 4; ++j)
        acc[i][j] = __builtin_amdgcn_mfma_f32_16x16x32_f16(a[i], b[j], acc[i][j], 0, 0, 0);
    __syncthreads();  // frag reads done before next k-step overwrites LDS
  }

  // epilogue: C/D layout col=lane&15, row=quad*4+reg (m89-verified mapping)
#pragma unroll
  for (int j = 0; j < 4; ++j) {
    const int gn = n0 + (wn * 4 + j) * 16 + col;
    const float bv = bias[gn];
#pragma unroll
    for (int i = 0; i < 4; ++i) {
      const long gm0 = m0 + (wm * 4 + i) * 16 + quad * 4;  // rows gm0..gm0+3
      if (MODE == 0) {
#pragma unroll
        for (int r = 0; r < 4; ++r)
          Y[(gm0 + r) * (long)N + gn] = (f16)((acc[i][j][r] + bv) * oscale);
      } else {
        const long bb = gm0 >> 10;            // batch
        const int kpos = (int)(gm0 & 1023);   // position within batch
        f16x4 ov;
#pragma unroll
        for (int r = 0; r < 4; ++r) ov[r] = (f16)((acc[i][j][r] + bv) * oscale);
        *(f16x4*)&Y[(bb * 2048 + gn) * 1024 + kpos] = ov;  // 8B store, aligned
      }
    }
  }
}

template <int MODE>
__global__ __launch_bounds__(256) void proj_gemm(
    const float* __restrict__ X, const float* __restrict__ W,
    const float* __restrict__ bias, f16* __restrict__ Y, int K, int N,
    float oscale) {
  __shared__ f16 Asf[4096];
  __shared__ f16 Bsf[4096];
  proj_body<MODE>(X, W, bias, Y, K, N, oscale, Asf, Bsf);
}

// q and k projections fused into one launch (grid.z selects) — doubles blocks
// in flight (256 -> 512; was 1 block/CU = 4 waves/CU, pure latency exposure).
__global__ __launch_bounds__(256) void proj_qk(
    const float* __restrict__ Xq, const float* __restrict__ Wq, const float* __restrict__ bq,
    const float* __restrict__ Xk, const float* __restrict__ Wk, const float* __restrict__ bk,
    f16* __restrict__ Yq, f16* __restrict__ Yk, float qscale) {
  __shared__ f16 Asf[4096];
  __shared__ f16 Bsf[4096];
  if (blockIdx.z == 0)
    proj_body<0>(Xq, Wq, bq, Yq, 512, 512, qscale, Asf, Bsf);
  else
    proj_body<0>(Xk, Wk, bk, Yk, 512, 512, 1.0f, Asf, Bsf);
}

// ---------------------------------------------------------------------------
// attn_fused: one block = (b, h, 16 q-rows). 256 threads = 4 waves.
// Latency-bound before (VALUBusy 17%, MfmaUtil 4%, HBM 24%): fixes are MLP.
//   QK phase: compile-time 16-trip loop, unroll 4 -> 4 bfrags + 16 mask dwords
//             in flight. qhat is pre-scaled by 1/sqrt(32) in the projection.
//   P stays UNNORMALIZED in LDS (f16, XOR granule swizzle). Row sums -> linv.
//   PV runs right after the rowsum barrier (unroll 4) and scales by linv[row]
//   in the epilogue (diag scaling commutes with PV) — no normalize write-back,
//   one barrier fewer, PV global loads start ~early.
//   attn_weights (normalized) streamed LAST with nontemporal stores; 576 MB of
//   never-re-read output no longer thrashes L2 ahead of PV's vhatT reads.
// Fixed-shift softmax (no max subtraction): identical to reference math.
// ---------------------------------------------------------------------------
__global__ __launch_bounds__(256, 4) void attn_fused(
    const f16* __restrict__ qhat, const f16* __restrict__ khat,
    const f16* __restrict__ vhatT, const float* __restrict__ mask,
    float* __restrict__ outO, float* __restrict__ outW) {
  __shared__ f16 P[16 * 1024];       // 32 KiB, unnormalized exp values
  __shared__ float lpart[4][16];
  __shared__ float linv16[16];

  const int t = threadIdx.x;
  const int lane = t & 63;
  const int w = t >> 6;
  const int quad = lane >> 4, col = lane & 15;
  const int qt = blockIdx.x;         // 0..63  -> q0 = qt*16
  const int bh = blockIdx.y;         // 0..127
  const int b = bh >> 4, h = bh & 15;
  const int q0 = qt * 16;

  // A fragment: q rows q0..q0+15, head dims h*32..h*32+31 (full contraction)
  const f16x8 afrag = *(const f16x8*)(qhat +
      ((long)(b * 1024 + q0 + col)) * 512 + h * 32 + quad * 8);

  const f32x4 zero = {0.f, 0.f, 0.f, 0.f};
  float lacc[4] = {0.f, 0.f, 0.f, 0.f};
  const long mrow0 = (long)b * 1024 + q0 + quad * 4;
  const f16* kbase = khat + ((long)b * 1024 + col) * 512 + h * 32 + quad * 8;

#pragma unroll 4
  for (int it = 0; it < 16; ++it) {
    const int nt = w + it * 4;
    const f16x8 bfrag = *(const f16x8*)(kbase + (long)nt * 16 * 512);
    const int kpos = nt * 16 + col;
    // mask loads issued before the mfma so they overlap it
    float mv[4];
#pragma unroll
    for (int r = 0; r < 4; ++r) mv[r] = mask[(mrow0 + r) * 1024 + kpos];
    f32x4 c = __builtin_amdgcn_mfma_f32_16x16x32_f16(afrag, bfrag, zero, 0, 0, 0);
    const int g = kpos >> 3;
#pragma unroll
    for (int r = 0; r < 4; ++r) {
      const float m = (mv[r] == 0.0f) ? -10000.0f : mv[r];  // masked_fill semantics
      const float e = __expf(c[r] + m);  // qhat pre-scaled: c already /sqrt(32)
      lacc[r] += e;
      const int qrow = quad * 4 + r;
      P[qrow * 1024 + ((g ^ (qrow & 7)) << 3) + (kpos & 7)] = (f16)e;
    }
  }

  // row sums: reduce over the 16 columns held across lane bits 0..3
#pragma unroll
  for (int r = 0; r < 4; ++r) {
    float v = lacc[r];
#pragma unroll
    for (int d = 1; d < 16; d <<= 1) v += __shfl_xor(v, d, 64);
    lacc[r] = v;
  }
  if (col == 0) {
#pragma unroll
    for (int r = 0; r < 4; ++r) lpart[w][quad * 4 + r] = lacc[r];
  }
  __syncthreads();                   // P + lpart ready
  if (t < 16)
    linv16[t] = 1.0f / (lpart[0][t] + lpart[1][t] + lpart[2][t] + lpart[3][t]);

  // PV on UNNORMALIZED P: O[16 x 128] = P @ V; wave w owns out cols w*32..+31
  f32x4 oacc0 = zero, oacc1 = zero;
  const f16* vbase = vhatT + ((long)b * 2048 + h * 128 + w * 32) * 1024;
  const f16* vb0 = vbase + (long)col * 1024 + quad * 8;
  const f16* vb1 = vbase + (long)(16 + col) * 1024 + quad * 8;
  const int prow = col * 1024;       // A-frag row = lane&15
  const int pxor = col & 7;
#pragma unroll 4
  for (int kc = 0; kc < 32; ++kc) {
    const f16x8 b0 = *(const f16x8*)(vb0 + kc * 32);
    const f16x8 b1 = *(const f16x8*)(vb1 + kc * 32);
    const f16x8 af = *(const f16x8*)&P[prow + (((kc * 4 + quad) ^ pxor) << 3)];
    oacc0 = __builtin_amdgcn_mfma_f32_16x16x32_f16(af, b0, oacc0, 0, 0, 0);
    oacc1 = __builtin_amdgcn_mfma_f32_16x16x32_f16(af, b1, oacc1, 0, 0, 0);
  }
  __syncthreads();                   // linv16 visible to all waves

  // O epilogue: deferred row normalization
#pragma unroll
  for (int r = 0; r < 4; ++r) {
    const float li = linv16[quad * 4 + r];
    const long orow =
        ((long)(b * 1024 + q0 + quad * 4 + r)) * 2048 + h * 128 + w * 32 + col;
    __builtin_nontemporal_store(oacc0[r] * li, &outO[orow]);
    __builtin_nontemporal_store(oacc1[r] * li, &outO[orow + 16]);
  }

  // attn_weights: normalize on the fly, stream out (coalesced f32x4, NT)
  float* wbase = outW + ((long)bh * 1024 + q0) * 1024;
#pragma unroll
  for (int i = 0; i < 8; ++i) {
    const int idx = i * 2048 + t * 8;
    const int row = idx >> 10;
    const int c0 = idx & 1023;
    const float li = linv16[row];
    const int poff = row * 1024 + ((((c0 >> 3) ^ (row & 7)) << 3));
    const f16x8 pv = *(const f16x8*)&P[poff];
    f32x4 o0, o1;
#pragma unroll
    for (int r = 0; r < 4; ++r) {
      o0[r] = (float)pv[r] * li;
      o1[r] = (float)pv[r + 4] * li;
    }
    __builtin_nontemporal_store(o0, (f32x4*)&wbase[(long)row * 1024 + c0]);
    __builtin_nontemporal_store(o1, (f32x4*)&wbase[(long)row * 1024 + c0 + 4]);
  }
}

// ---------------------------------------------------------------------------
extern "C" void kernel_launch(void* const* d_in, const int* in_sizes, int n_in,
                              void* d_out, int out_size, void* d_ws, size_t ws_size,
                              hipStream_t stream) {
  const float* query = (const float*)d_in[0];
  const float* key   = (const float*)d_in[1];
  const float* value = (const float*)d_in[2];
  const float* mask  = (const float*)d_in[3];
  const float* qW = (const float*)d_in[4];
  const float* qb = (const float*)d_in[5];
  const float* kW = (const float*)d_in[6];
  const float* kb = (const float*)d_in[7];
  const float* vW = (const float*)d_in[8];
  const float* vb = (const float*)d_in[9];

  float* outO = (float*)d_out;                        // [8][1024][2048]
  float* outW = outO + (size_t)8 * 1024 * 2048;       // [8][16][1024][1024]

  char* ws = (char*)d_ws;                             // needs 48 MiB
  f16* qhat  = (f16*)ws;                              // [8192][512], pre-scaled
  f16* khat  = (f16*)(ws + ((size_t)8 << 20));        // [8192][512]
  f16* vhatT = (f16*)(ws + ((size_t)16 << 20));       // [8][2048][1024]

  const float sc = 0.17677669529663687f;              // 1/sqrt(32)
  proj_qk<<<dim3(64, 4, 2), 256, 0, stream>>>(query, qW, qb, key, kW, kb,
                                              qhat, khat, sc);
  proj_gemm<1><<<dim3(64, 16), 256, 0, stream>>>(value, vW, vb, vhatT, 2048, 2048, 1.0f);
  attn_fused<<<dim3(64, 128), 256, 0, stream>>>(qhat, khat, vhatT, mask, outO, outW);
}